// Round 7
// baseline (5916.960 us; speedup 1.0000x reference)
//
#include <hip/hip_runtime.h>

#define N_NEUR 4096
#define B_SZ   64
#define T_STEPS 128
#define N_CLS  10

typedef double d4v __attribute__((ext_vector_type(4)));

// ---------------- layout probe: find consistent (A,B,D) lane maps for f64 MFMA ----------------
__global__ void kernProbe(int* __restrict__ combo_out) {
    int l = threadIdx.x;
    int best = -1;
    for (int c = 0; c < 16; ++c) {
        int amap = c & 1, bmap = (c >> 1) & 1, dmap = (c >> 2) & 3;
        int ai = amap ? (l >> 2) : (l & 15);
        int ak = amap ? (l & 3)  : (l >> 4);
        int bk = bmap ? (l & 3)  : (l >> 4);
        int bj = bmap ? (l >> 2) : (l & 15);
        double a = (double)(ai * 4 + ak + 1);
        double b = (double)(bk * 16 + bj + 1);
        d4v d = {0.0, 0.0, 0.0, 0.0};
        d = __builtin_amdgcn_mfma_f64_16x16x4f64(a, b, d, 0, 0, 0);
        bool ok = true;
        #pragma unroll
        for (int r = 0; r < 4; ++r) {
            int di, dj;
            if      (dmap == 0) { di = 4 * (l >> 4) + r; dj = l & 15; }
            else if (dmap == 1) { di = l & 15; dj = 4 * (l >> 4) + r; }
            else if (dmap == 2) { di = (l >> 4) + 4 * r; dj = l & 15; }
            else                { di = l & 15; dj = (l >> 4) + 4 * r; }
            double ref = 0.0;
            for (int k = 0; k < 4; ++k)
                ref += (double)(di * 4 + k + 1) * (double)(k * 16 + dj + 1);
            ok = ok && (d[r] == ref);
        }
        unsigned long long m = __ballot(ok);
        if (m == ~0ull && best < 0) best = c;
    }
    if (l == 0) combo_out[0] = (best < 0) ? 0 : best;
}

// ---------------- pack W into group-packed layout (combo-independent) ----------------
// Wf4[(g*4096 + n)*16 + 4*(k&3) + ((k>>2)&3)] = W[n][k],  g = k>>4
__global__ __launch_bounds__(256) void kernP(const float* __restrict__ W, float* __restrict__ Wf4) {
    const int g = blockIdx.x;                      // 0..255
    for (int n = threadIdx.x; n < N_NEUR; n += 256) {
        const float* src = W + (size_t)n * N_NEUR + 16 * g;
        float4 in0 = *(const float4*)(src + 0);
        float4 in1 = *(const float4*)(src + 4);
        float4 in2 = *(const float4*)(src + 8);
        float4 in3 = *(const float4*)(src + 12);
        float* dst = Wf4 + ((size_t)g * N_NEUR + n) * 16;
        // inner = 4*e + c  where k = 16g + 4c + e
        float4 o0 = {in0.x, in1.x, in2.x, in3.x};
        float4 o1 = {in0.y, in1.y, in2.y, in3.y};
        float4 o2 = {in0.z, in1.z, in2.z, in3.z};
        float4 o3 = {in0.w, in1.w, in2.w, in3.w};
        *(float4*)(dst + 0)  = o0;
        *(float4*)(dst + 4)  = o1;
        *(float4*)(dst + 8)  = o2;
        *(float4*)(dst + 12) = o3;
    }
}

__device__ __forceinline__ size_t sfb_pos(int n, int b) {
    return ((size_t)(n >> 4) * 64 + b) * 16 + 4 * (n & 3) + ((n >> 2) & 3);
}

// ---------------- t=0 init ----------------
__global__ __launch_bounds__(256) void kernI(const float* __restrict__ x,
                                             const float* __restrict__ Win,
                                             double* __restrict__ vr,
                                             float* __restrict__ sf,
                                             float* __restrict__ sT) {
    int idx = blockIdx.x * 256 + threadIdx.x;
    int b = idx & 63, n = idx >> 6;
    double v = (double)x[b * T_STEPS] * (double)Win[n];
    bool sp = (v >= 1.0);
    vr[idx] = sp ? 0.0 : v;
    float s = sp ? 1.0f : 0.0f;
    sT[idx] = s;
    sf[sfb_pos(n, b)] = s;
}

// ---------------- fused: recurrent GEMM (f64 MFMA) + LIF  |  classifier for step t-1 ----------------
template<bool USEWF>
__global__ __launch_bounds__(1024) void kernAB(const float* __restrict__ Wsrc,  // USEWF ? Wf4 : Wres[n][m]
                                               const float* __restrict__ sfp,   // prev spikes, sfB layout
                                               const float* __restrict__ x,
                                               const float* __restrict__ Win,
                                               double* __restrict__ vr,
                                               float* __restrict__ sfc,
                                               float* __restrict__ sTc,
                                               const float* __restrict__ sTp,
                                               const float* __restrict__ Wout,
                                               double* __restrict__ vc,
                                               double* __restrict__ counts,
                                               const int* __restrict__ combo_p,
                                               int t) {
    __shared__ double lbuf[4][16 * 64];
    __shared__ double red[16][N_CLS];
    const int tid  = threadIdx.x;
    const int wave = tid >> 6, lane = tid & 63;

    if (blockIdx.x >= 256) {
        // ---- classifier path: step t-1, batch b ----
        const int b = blockIdx.x - 256;
        double part[N_CLS];
        #pragma unroll
        for (int c = 0; c < N_CLS; ++c) part[c] = 0.0;
        for (int m = tid; m < N_NEUR; m += 1024) {
            double s = (double)sTp[(size_t)m * B_SZ + b];
            #pragma unroll
            for (int c = 0; c < N_CLS; ++c)
                part[c] = fma(s, (double)Wout[c * N_NEUR + m], part[c]);
        }
        #pragma unroll
        for (int c = 0; c < N_CLS; ++c) {
            double v = part[c];
            for (int off = 32; off > 0; off >>= 1)
                v += __shfl_down(v, off, 64);
            if (lane == 0) red[wave][c] = v;
        }
        __syncthreads();
        if (tid < N_CLS) {
            double tot = 0.0;
            #pragma unroll
            for (int wv = 0; wv < 16; ++wv) tot += red[wv][tid];
            double v = 0.9 * vc[b * N_CLS + tid] + tot;
            bool sp = (v >= 1.0);
            vc[b * N_CLS + tid] = sp ? 0.0 : v;
            if (sp) counts[b * N_CLS + tid] += 1.0;
        }
        return;
    }

    // ---- GEMM + LIF path ----
    const int wb = wave & 3, wq = wave >> 2;
    const int gn0 = blockIdx.x * 16;
    const int combo = combo_p[0];
    const int amap = combo & 1, bmap = (combo >> 1) & 1, dmap = (combo >> 2) & 3;
    const int ai = amap ? (lane >> 2) : (lane & 15);
    const int ak = amap ? (lane & 3)  : (lane >> 4);
    const int bk = bmap ? (lane & 3)  : (lane >> 4);
    const int bj = bmap ? (lane >> 2) : (lane & 15);

    d4v acc0 = {0.0, 0.0, 0.0, 0.0};
    d4v acc1 = {0.0, 0.0, 0.0, 0.0};

    if (USEWF) {
        // group-packed: per blk one float4 per operand
        const float* ap = Wsrc + ((size_t)(64 * wq) * N_NEUR + gn0 + ai) * 16 + 4 * ak;
        const float* bp = sfp + ((size_t)(64 * wq) * 64 + 16 * wb + bj) * 16 + 4 * bk;
        float4 av = *(const float4*)ap;
        float4 bv = *(const float4*)bp;
        for (int blk = 0; blk < 64; ++blk) {
            float4 ac = av, bc = bv;
            ap += (size_t)N_NEUR * 16;
            bp += 64 * 16;
            if (blk < 63) {
                av = *(const float4*)ap;
                bv = *(const float4*)bp;
            }
            acc0 = __builtin_amdgcn_mfma_f64_16x16x4f64((double)ac.x, (double)bc.x, acc0, 0, 0, 0);
            acc1 = __builtin_amdgcn_mfma_f64_16x16x4f64((double)ac.y, (double)bc.y, acc1, 0, 0, 0);
            acc0 = __builtin_amdgcn_mfma_f64_16x16x4f64((double)ac.z, (double)bc.z, acc0, 0, 0, 0);
            acc1 = __builtin_amdgcn_mfma_f64_16x16x4f64((double)ac.w, (double)bc.w, acc1, 0, 0, 0);
        }
    } else {
        const int q0 = wq * 256;
        const float* bp = sfp + ((size_t)(64 * wq) * 64 + 16 * wb + bj) * 16 + 4 * bk;
        #pragma unroll 4
        for (int q = 0; q < 256; ++q) {
            int g = q >> 2, u = q & 3;
            double a  = (double)Wsrc[(size_t)(gn0 + ai) * N_NEUR + 4 * (q0 + q) + ak];
            double bv = (double)bp[(size_t)g * 1024 + u];
            acc0 = __builtin_amdgcn_mfma_f64_16x16x4f64(a, bv, acc0, 0, 0, 0);
        }
    }

    {
        const int jb = 16 * wb;
        #pragma unroll
        for (int r = 0; r < 4; ++r) {
            int di, dj;
            if      (dmap == 0) { di = 4 * (lane >> 4) + r; dj = lane & 15; }
            else if (dmap == 1) { di = lane & 15; dj = 4 * (lane >> 4) + r; }
            else if (dmap == 2) { di = (lane >> 4) + 4 * r; dj = lane & 15; }
            else                { di = lane & 15; dj = (lane >> 4) + 4 * r; }
            lbuf[wq][di * 64 + jb + dj] = acc0[r] + acc1[r];
        }
    }
    __syncthreads();

    int nl = tid >> 6, b = tid & 63;
    int n = gn0 + nl;
    size_t gidx = (size_t)n * 64 + b;
    double cur = lbuf[0][tid] + lbuf[1][tid] + lbuf[2][tid] + lbuf[3][tid]
               + (double)x[b * T_STEPS + t] * (double)Win[n];
    double v = 0.9 * vr[gidx] + cur;
    bool sp = (v >= 1.0);
    vr[gidx] = sp ? 0.0 : v;
    float s = sp ? 1.0f : 0.0f;
    sTc[gidx] = s;
    sfc[sfb_pos(n, b)] = s;
}

// ---------------- standalone classifier (final step) ----------------
__global__ __launch_bounds__(256) void kernC(const float* __restrict__ sT,
                                             const float* __restrict__ Wout,
                                             double* __restrict__ vc,
                                             double* __restrict__ counts) {
    int b = blockIdx.x;
    int tid = threadIdx.x;
    double part[N_CLS];
    #pragma unroll
    for (int c = 0; c < N_CLS; ++c) part[c] = 0.0;
    for (int m = tid; m < N_NEUR; m += 256) {
        double s = (double)sT[(size_t)m * B_SZ + b];
        #pragma unroll
        for (int c = 0; c < N_CLS; ++c)
            part[c] = fma(s, (double)Wout[c * N_NEUR + m], part[c]);
    }
    __shared__ double red[4][N_CLS];
    int lane = tid & 63, wv = tid >> 6;
    #pragma unroll
    for (int c = 0; c < N_CLS; ++c) {
        double v = part[c];
        for (int off = 32; off > 0; off >>= 1)
            v += __shfl_down(v, off, 64);
        if (lane == 0) red[wv][c] = v;
    }
    __syncthreads();
    if (tid < N_CLS) {
        double tot = red[0][tid] + red[1][tid] + red[2][tid] + red[3][tid];
        double v = 0.9 * vc[b * N_CLS + tid] + tot;
        bool sp = (v >= 1.0);
        vc[b * N_CLS + tid] = sp ? 0.0 : v;
        if (sp) counts[b * N_CLS + tid] += 1.0;
    }
}

__global__ void kernD(const double* __restrict__ counts, float* __restrict__ out) {
    int i = blockIdx.x * blockDim.x + threadIdx.x;
    if (i < B_SZ * N_CLS) out[i] = (float)counts[i];
}

extern "C" void kernel_launch(void* const* d_in, const int* in_sizes, int n_in,
                              void* d_out, int out_size, void* d_ws, size_t ws_size,
                              hipStream_t stream) {
    const float* x    = (const float*)d_in[0];
    const float* Win  = (const float*)d_in[1];
    const float* Wres = (const float*)d_in[2];
    const float* Wout = (const float*)d_in[3];
    float* out = (float*)d_out;

    const size_t NB = (size_t)B_SZ * N_NEUR;
    char* w = (char*)d_ws;
    double* vr     = (double*)w;  w += NB * sizeof(double);
    float*  sTa    = (float*)w;   w += NB * sizeof(float);
    float*  sTb    = (float*)w;   w += NB * sizeof(float);
    float*  sf0    = (float*)w;   w += NB * sizeof(float);
    float*  sf1    = (float*)w;   w += NB * sizeof(float);
    double* vc     = (double*)w;  w += (size_t)B_SZ * N_CLS * sizeof(double);
    double* counts = (double*)w;  w += (size_t)B_SZ * N_CLS * sizeof(double);
    int*    combo  = (int*)w;     w += 256;
    float*  Wf4    = (float*)w;   // 64 MB group-packed W

    size_t fixed = (size_t)(w - (char*)d_ws);
    bool use_wf = (ws_size >= fixed + (size_t)N_NEUR * N_NEUR * sizeof(float));

    hipMemsetAsync(vc, 0, 2ull * B_SZ * N_CLS * sizeof(double), stream);

    kernProbe<<<dim3(1), 64, 0, stream>>>(combo);
    if (use_wf)
        kernP<<<dim3(256), 256, 0, stream>>>(Wres, Wf4);

    kernI<<<dim3(NB / 256), 256, 0, stream>>>(x, Win, vr, sf0, sTa);
    for (int t = 1; t < T_STEPS; ++t) {
        const float* sfp = (t & 1) ? sf0 : sf1;
        float*       sfc = (t & 1) ? sf1 : sf0;
        float*       sTc = (t & 1) ? sTb : sTa;
        const float* sTp = (t & 1) ? sTa : sTb;
        if (use_wf)
            kernAB<true><<<dim3(320), 1024, 0, stream>>>(Wf4, sfp, x, Win, vr, sfc, sTc, sTp,
                                                         Wout, vc, counts, combo, t);
        else
            kernAB<false><<<dim3(320), 1024, 0, stream>>>(Wres, sfp, x, Win, vr, sfc, sTc, sTp,
                                                          Wout, vc, counts, combo, t);
    }
    kernC<<<dim3(B_SZ), 256, 0, stream>>>(sTb, Wout, vc, counts);  // t = 127 (odd -> sTb)
    kernD<<<dim3(3), 256, 0, stream>>>(counts, out);
}